// Round 11
// baseline (333.136 us; speedup 1.0000x reference)
//
#include <hip/hip_runtime.h>
#include <math.h>

#define NLAT 64
#define NLON 128
#define HID  256
#define NSTA 1024
#define NG   8192          // grid points per batch
#define TABN 4096
#define TABW 4.5f
#define CLS_MARGIN 4.55f

#define LOG2E 1.4426950408889634f
#define LN2   0.69314718055994531f

typedef float f32x4 __attribute__((ext_vector_type(4)));
typedef _Float16 f16x8 __attribute__((ext_vector_type(8)));

// accurate gelu for table build (A&S 7.1.26, |erf err| <= 1.5e-7)
__device__ __forceinline__ float gelu_ref(float x) {
    const float p  = 0.3275911f;
    const float a1 = 0.254829592f, a2 = -0.284496736f, a3 = 1.421413741f,
                a4 = -1.453152027f, a5 = 1.061405429f;
    float z  = x * 0.70710678118654752f;
    float az = fabsf(z);
    float t  = __builtin_amdgcn_rcpf(fmaf(p, az, 1.0f));
    float poly = fmaf(fmaf(fmaf(fmaf(a5, t, a4), t, a3), t, a2), t, a1) * t;
    float e  = __builtin_amdgcn_exp2f(az * az * -LOG2E);
    float r  = fmaf(-poly, e, 1.0f);
    float erfz = copysignf(r, z);
    float hx = 0.5f * x;
    return fmaf(hx, erfz, hx);
}

// ---- Kernel 0: feats [b][s][d] f32 -> F^T hi/lo [b][d][s] f16 (split for precision)
__global__ __launch_bounds__(256)
void cvt_kernel(const float* __restrict__ feats, _Float16* __restrict__ fhi,
                _Float16* __restrict__ flo) {
    __shared__ float tile[64][68];
    const int blk = blockIdx.x;            // b(2) * st(16) * dt(4)
    const int b  = blk >> 6;
    const int st = (blk >> 2) & 15;        // station tile of 64
    const int dt = blk & 3;                // d tile of 64
    {
        const int dq = threadIdx.x & 15;   // float4 col
        const int sr = threadIdx.x >> 4;   // 0..15
#pragma unroll
        for (int k = 0; k < 4; ++k) {
            int s = k * 16 + sr;
            float4 vv = *(const float4*)
                &feats[((size_t)(b * NSTA + st * 64 + s)) * HID + dt * 64 + dq * 4];
            *(float4*)&tile[s][dq * 4] = vv;
        }
    }
    __syncthreads();
    const int d  = threadIdx.x >> 2;       // 0..63
    const int sg = threadIdx.x & 3;        // station subgroup of 16
    f16x8 h8[2], l8[2];
#pragma unroll
    for (int k = 0; k < 16; ++k) {
        float v = tile[sg * 16 + k][d];
        _Float16 h = (_Float16)v;
        h8[k >> 3][k & 7] = h;
        l8[k >> 3][k & 7] = (_Float16)(v - (float)h);
    }
    const size_t o = ((size_t)(b * HID + dt * 64 + d)) * NSTA + st * 64 + sg * 16;
    *(f16x8*)&fhi[o]     = h8[0];
    *(f16x8*)&fhi[o + 8] = h8[1];
    *(f16x8*)&flo[o]     = l8[0];
    *(f16x8*)&flo[o + 8] = l8[1];
}

// ---- Kernel 1: scores + softmax -> normalized f16 weights Wn[b][g][s]
// One wave per (b,g) x4 sequential. In-wave softmax (shuffle reduce), no barriers
// in the main loop. Per-g interval classification (point lonv -> tight intervals).
// (256,4): VGPR cap 128; live arrays = 48 regs. NEVER (256,8): spills (r7/r8).
__global__ __launch_bounds__(256, 4)
void score_kernel(const float* __restrict__ coords,  // [2][1024][3]
                  const float* __restrict__ maskp,   // [2][1024]
                  const float* __restrict__ W1,      // [3][32]
                  const float* __restrict__ b1,      // [32]
                  const float* __restrict__ W2,      // [32]
                  const float* __restrict__ b2p,     // [1]
                  _Float16* __restrict__ wn)         // [2][8192][1024]
{
    __shared__ __align__(8) float gtab[TABN];        // 16 KB: gelu(x)-relu(x), nearest
    __shared__ __align__(16) float slat[NSTA], slon[NSTA], smask[NSTA];  // 12 KB
    __shared__ float4 wpack[32];                     // (W1row0, W1row1, W1row2, b1)
    __shared__ float w2s[32];
    __shared__ int nlidxS[4][32];                    // per-wave nonlinear j list

    const int tid  = threadIdx.x;
    const int b    = blockIdx.x >> 9;      // 1024 blocks = 2 b * 512 g-tiles of 16
    const int g0   = (blockIdx.x & 511) * 16;
    const int lane = tid & 63;
    const int wv   = tid >> 6;

    const float TH = 2.0f * TABW / (float)TABN;
    for (int k = tid; k < TABN; k += 256) {
        float x = -TABW + ((float)k + 0.5f) * TH;
        gtab[k] = gelu_ref(x) - fmaxf(x, 0.0f);
    }
    if (tid < 32) {
        wpack[tid] = make_float4(W1[tid], W1[32 + tid], W1[64 + tid], b1[tid]);
        w2s[tid]   = W2[tid];
    }
    const float b2 = b2p[0];
    {
        const float* cb = coords + (size_t)b * NSTA * 3;
        const float* mb = maskp  + (size_t)b * NSTA;
        for (int k = tid; k < NSTA; k += 256) {
            slat[k]  = cb[k * 3 + 0];
            slon[k]  = cb[k * 3 + 1];
            smask[k] = mb[k];
        }
    }
    __syncthreads();

    // batch-wide station bounds (wave-uniform after reduce)
    float lamin = 1.0e30f, lamax = -1.0e30f, lomin = 1.0e30f, lomax = -1.0e30f;
#pragma unroll 4
    for (int i = 0; i < 16; ++i) {
        float la = slat[i * 64 + lane];
        float lo = slon[i * 64 + lane];
        lamin = fminf(lamin, la); lamax = fmaxf(lamax, la);
        lomin = fminf(lomin, lo); lomax = fmaxf(lomax, lo);
    }
#pragma unroll
    for (int off = 32; off >= 1; off >>= 1) {
        lamin = fminf(lamin, __shfl_xor(lamin, off));
        lamax = fmaxf(lamax, __shfl_xor(lamax, off));
        lomin = fminf(lomin, __shfl_xor(lomin, off));
        lomax = fmaxf(lomax, __shfl_xor(lomax, off));
    }

    const float ISCALE = (float)TABN / (2.0f * TABW);
    const float IOFF   = (float)TABN * 0.5f;

    for (int it = 0; it < 4; ++it) {
        const int g = g0 + wv * 4 + it;
        const float latv = -90.0f + (180.0f / 63.0f) * (float)(g >> 7);
        const float lonv = -180.0f + (360.0f / 127.0f) * (float)(g & 127);

        // ---- classification: all 64 lanes, j duplicated across halves
        const int jj = lane & 31;
        float4 wj = wpack[jj];
        float w2j = w2s[jj];
        float dla_lo = lamin - latv, dla_hi = lamax - latv;
        float dlo_lo = lomin - lonv, dlo_hi = lomax - lonv;
        float a2a = dla_lo * dla_lo, a2b = dla_hi * dla_hi;
        float a2lo = (dla_lo > 0.0f) ? a2a : ((dla_hi < 0.0f) ? a2b : 0.0f);
        float a2hi = fmaxf(a2a, a2b);
        float b2a = dlo_lo * dlo_lo, b2b = dlo_hi * dlo_hi;
        float b2lo = (dlo_lo > 0.0f) ? b2a : ((dlo_hi < 0.0f) ? b2b : 0.0f);
        float b2hi = fmaxf(b2a, b2b);
        float d_lo = sqrtf(a2lo + b2lo + 1e-6f);
        float d_hi = sqrtf(a2hi + b2hi + 1e-6f);
        float pxl = fminf(wj.x * d_lo, wj.x * d_hi), pxh = fmaxf(wj.x * d_lo, wj.x * d_hi);
        float pyl = fminf(wj.y * dla_lo, wj.y * dla_hi), pyh = fmaxf(wj.y * dla_lo, wj.y * dla_hi);
        float pzl = fminf(wj.z * dlo_lo, wj.z * dlo_hi), pzh = fmaxf(wj.z * dlo_lo, wj.z * dlo_hi);
        float plo = wj.w + pxl + pyl + pzl;
        float phi = wj.w + pxh + pyh + pzh;
        bool isLin = (plo > CLS_MARGIN);
        bool isNL  = (!isLin) && (phi >= -CLS_MARGIN);
        // linear collapse coeffs; xor {16..1} reduces within each 32-half; halves
        // identical -> every lane holds the 32-sum, no broadcast needed
        float cx = isLin ? w2j * wj.x : 0.0f;
        float cy = isLin ? w2j * wj.y : 0.0f;
        float cz = isLin ? w2j * wj.z : 0.0f;
        float cc = isLin ? w2j * wj.w : 0.0f;
#pragma unroll
        for (int off = 16; off >= 1; off >>= 1) {
            cx += __shfl_xor(cx, off);
            cy += __shfl_xor(cy, off);
            cz += __shfl_xor(cz, off);
            cc += __shfl_xor(cc, off);
        }
        unsigned long long mb64 = __ballot(isNL);
        unsigned mlow = (unsigned)(mb64 & 0xffffffffull);
        const int nn = __popc(mlow);
        if (lane < 32 && isNL) {
            int pos = __popc(mlow & ((1u << lane) - 1u));
            nlidxS[wv][pos] = jj;   // DS ops same-wave are ordered; no barrier needed
        }

        // ---- eval: 16 stations per lane (s = i*64 + lane)
        float dist[16], dla[16], vsc[16];
        const float vb = b2 + cc;
#pragma unroll 4
        for (int i = 0; i < 16; ++i) {
            int s = i * 64 + lane;
            float a = slat[s] - latv;
            float o = slon[s] - lonv;
            float dd = sqrtf(fmaf(a, a, fmaf(o, o, 1e-6f)));
            dla[i] = a;
            dist[i] = dd;
            vsc[i] = fmaf(cx, dd, fmaf(cy, a, fmaf(cz, o, vb)));
        }
        for (int k = 0; k < nn; ++k) {
            int j = nlidxS[wv][k];
            float4 w = wpack[j];
            float  w2 = w2s[j];
#pragma unroll 4
            for (int i = 0; i < 16; ++i) {
                float o = slon[i * 64 + lane] - lonv;
                float pre = fmaf(w.x, dist[i], fmaf(w.y, dla[i], fmaf(w.z, o, w.w)));
                float cl  = fminf(fmaxf(pre, -TABW), 4.49945f);
                int  idx  = (int)fmaf(cl, ISCALE, IOFF);
                vsc[i] = fmaf(w2, fmaxf(pre, 0.0f) + gtab[idx], vsc[i]);
            }
        }
        // ---- softplus * mask, in-wave softmax, normalized f16 write
        float mx = -3.0e38f;
#pragma unroll 4
        for (int i = 0; i < 16; ++i) {
            int s = i * 64 + lane;
            float x  = vsc[i];
            float ax = fabsf(x);
            float e  = __builtin_amdgcn_exp2f(-ax * LOG2E);
            float sp = fmaxf(x, 0.0f) + __builtin_amdgcn_logf(1.0f + e) * LN2;
            vsc[i] = sp * smask[s];
            mx = fmaxf(mx, vsc[i]);
        }
#pragma unroll
        for (int off = 32; off >= 1; off >>= 1) mx = fmaxf(mx, __shfl_xor(mx, off));
        float sum = 0.0f;
#pragma unroll 4
        for (int i = 0; i < 16; ++i) {
            float p = __builtin_amdgcn_exp2f((vsc[i] - mx) * LOG2E);
            vsc[i] = p;
            sum += p;
        }
#pragma unroll
        for (int off = 32; off >= 1; off >>= 1) sum += __shfl_xor(sum, off);
        float rl = __builtin_amdgcn_rcpf(sum);   // ~1 ulp, negligible vs f16 round
        _Float16* wp = wn + ((size_t)(b * NG + g)) * NSTA;
#pragma unroll 4
        for (int i = 0; i < 16; ++i)
            wp[i * 64 + lane] = (_Float16)(vsc[i] * rl);
    }
}

// ---- Kernel 2: pure MFMA GEMM, no LDS. out[b][d][g] = sum_s Wn[b][g][s]*F[b][s][d]
// A-frag = Wn rows (m=g), B-frag = F^T rows (n=d), both k-major f16x8 direct loads.
__global__ __launch_bounds__(256)
void gemm_kernel(const _Float16* __restrict__ wn,   // [2][8192][1024]
                 const _Float16* __restrict__ fhi,  // [2][256][1024]
                 const _Float16* __restrict__ flo,  // [2][256][1024]
                 float* __restrict__ out)           // [2][256][8192]
{
    const int blk  = blockIdx.x;           // 512 = 2 b * 256 g-tiles of 32
    const int b    = blk >> 8;
    const int gt   = (blk & 255) * 32;
    const int lane = threadIdx.x & 63;
    const int wv   = threadIdx.x >> 6;     // d-range wv*64
    const int dsel = wv * 64;
    const int quad = lane >> 4;
    const int nidx = lane & 15;

    f32x4 acc[2][4];
#pragma unroll
    for (int m = 0; m < 2; ++m)
#pragma unroll
        for (int t = 0; t < 4; ++t) acc[m][t] = (f32x4){0.0f, 0.0f, 0.0f, 0.0f};

    const _Float16* wb  = wn  + ((size_t)(b * NG + gt)) * NSTA;
    const _Float16* fhb = fhi + (size_t)b * HID * NSTA;
    const _Float16* flb = flo + (size_t)b * HID * NSTA;

#pragma unroll 4
    for (int kc = 0; kc < 32; ++kc) {
        const int soff = kc * 32 + quad * 8;
        f16x8 a0 = *(const f16x8*)(wb + (size_t)nidx * NSTA + soff);
        f16x8 a1 = *(const f16x8*)(wb + (size_t)(nidx + 16) * NSTA + soff);
#pragma unroll
        for (int t = 0; t < 4; ++t) {
            const size_t fo = (size_t)(dsel + t * 16 + nidx) * NSTA + soff;
            f16x8 bh = *(const f16x8*)(fhb + fo);
            f16x8 bl = *(const f16x8*)(flb + fo);
            acc[0][t] = __builtin_amdgcn_mfma_f32_16x16x32_f16(a0, bh, acc[0][t], 0, 0, 0);
            acc[0][t] = __builtin_amdgcn_mfma_f32_16x16x32_f16(a0, bl, acc[0][t], 0, 0, 0);
            acc[1][t] = __builtin_amdgcn_mfma_f32_16x16x32_f16(a1, bh, acc[1][t], 0, 0, 0);
            acc[1][t] = __builtin_amdgcn_mfma_f32_16x16x32_f16(a1, bl, acc[1][t], 0, 0, 0);
        }
    }

    // C layout: col = d = lane&15, row = g-in-tile = quad*4 + reg -> float4 covers
    // 4 consecutive g (= consecutive lons; gt%32==0 keeps tiles within a lat row)
#pragma unroll
    for (int m = 0; m < 2; ++m) {
#pragma unroll
        for (int t = 0; t < 4; ++t) {
            const int d = dsel + t * 16 + nidx;
            float* op = out + ((size_t)(b * HID + d)) * NG + gt + m * 16 + quad * 4;
            *reinterpret_cast<float4*>(op) = *(float4*)&acc[m][t];
        }
    }
}

extern "C" void kernel_launch(void* const* d_in, const int* in_sizes, int n_in,
                              void* d_out, int out_size, void* d_ws, size_t ws_size,
                              hipStream_t stream) {
    const float* feats  = (const float*)d_in[0];
    const float* coords = (const float*)d_in[1];
    const float* maskp  = (const float*)d_in[2];
    const float* W1     = (const float*)d_in[3];
    const float* b1     = (const float*)d_in[4];
    const float* W2     = (const float*)d_in[5];
    const float* b2     = (const float*)d_in[6];
    float* out          = (float*)d_out;

    _Float16* fhi = (_Float16*)d_ws;                     // [2][256][1024] = 1 MB
    _Float16* flo = fhi + (size_t)2 * HID * NSTA;        // [2][256][1024] = 1 MB
    _Float16* wn  = flo + (size_t)2 * HID * NSTA;        // [2][8192][1024] = 32 MB

    hipLaunchKernelGGL(cvt_kernel,   dim3(128),  dim3(256), 0, stream, feats, fhi, flo);
    hipLaunchKernelGGL(score_kernel, dim3(1024), dim3(256), 0, stream,
                       coords, maskp, W1, b1, W2, b2, wn);
    hipLaunchKernelGGL(gemm_kernel,  dim3(512),  dim3(256), 0, stream,
                       wn, fhi, flo, out);
}